// Round 1
// baseline (125.478 us; speedup 1.0000x reference)
//
#include <hip/hip_runtime.h>
#include <float.h>

// Problem constants: E=4, L=8, S=512, F=32, SAMPLE_SIZE=512 grid points.

#if __has_builtin(__builtin_amdgcn_exp2f)
__device__ __forceinline__ float fast_exp2(float x) { return __builtin_amdgcn_exp2f(x); }
#else
__device__ __forceinline__ float fast_exp2(float x) { return exp2f(x); }
#endif

// ---- workspace layout (float offsets) ----
#define PT_OFF    0        // proj^T [E][L][F][S] = 524288 floats (UNscaled by 1/std)
#define STD_OFF   524288   // 32 per-(e,l) std sums
#define MIN_OFF   524320   // 256 per-block proj mins
#define MAX_OFF   524576   // 256 per-block proj maxs
#define CONST_OFF 524832   // 16 scalars
#define PAIR_OFF  524848   // 6*8*32 = 1536 pair sums
// total 526384 floats = ~2.1 MB of d_ws

// consts: [0]=std [1]=1/std [2]=left [3]=right [4]=delta [5]=scale [6]=negc [7]=gstep

// ---------------- stage 1: per-(e,l,f) std, summed per (e,l) ----------------
__global__ __launch_bounds__(256) void stage_std(const float* __restrict__ matrix,
                                                 float* __restrict__ stdsum) {
    const int el = blockIdx.x;          // 0..31
    const int t = threadIdx.x;
    const int f = t & 31, r = t >> 5;   // r in 0..7
    const float* base = matrix + (size_t)el * 512 * 32;
    float sx = 0.f, sxx = 0.f;
    for (int s = r; s < 512; s += 8) {
        float v = base[s * 32 + f];
        sx += v; sxx += v * v;
    }
    __shared__ float shx[256], shxx[256];
    shx[t] = sx; shxx[t] = sxx;
    __syncthreads();
    if (t < 32) {
        float a = 0.f, b = 0.f;
        for (int k = 0; k < 8; ++k) { a += shx[k * 32 + t]; b += shxx[k * 32 + t]; }
        float mean = a * (1.0f / 512.0f);
        float var = (b - a * mean) * (1.0f / 511.0f);   // ddof=1
        shx[t] = sqrtf(fmaxf(var, 0.f));
    }
    __syncthreads();
    if (t == 0) {
        float s = 0.f;
        for (int k = 0; k < 32; ++k) s += shx[k];
        stdsum[el] = s;
    }
}

// ---------------- stage 2: proj = matrix @ params, store transposed, min/max ----------------
__global__ __launch_bounds__(256) void stage_proj(const float* __restrict__ matrix,
                                                  const float* __restrict__ params,
                                                  float* __restrict__ PT,
                                                  float* __restrict__ minp,
                                                  float* __restrict__ maxp) {
    __shared__ float M[64][33];   // +1 pad breaks stride-32 bank aliasing
    __shared__ float Pm[32][32];  // params[f'][g] — broadcast reads, no pad needed
    __shared__ float rmin[4], rmax[4];
    const int bid = blockIdx.x;       // 256 blocks = (e*8+l)*8 + stile
    const int s0 = (bid & 7) << 6;
    const int el = bid >> 3;
    const int t = threadIdx.x;
    for (int k = t; k < 1024; k += 256) Pm[k >> 5][k & 31] = params[k];
    const float* mb = matrix + (size_t)(el * 512 + s0) * 32;
    for (int k = t; k < 2048; k += 256) M[k >> 5][k & 31] = mb[k];
    __syncthreads();
    const int s = t & 63;
    const int g0 = t >> 6;            // wave-uniform -> Pm reads broadcast
    float lmin = FLT_MAX, lmax = -FLT_MAX;
    #pragma unroll
    for (int pass = 0; pass < 8; ++pass) {
        const int g = (pass << 2) + g0;
        float acc = 0.f;
        #pragma unroll
        for (int fp = 0; fp < 32; ++fp) acc += M[s][fp] * Pm[fp][g];
        lmin = fminf(lmin, acc);
        lmax = fmaxf(lmax, acc);
        PT[(size_t)(el * 32 + g) * 512 + s0 + s] = acc;   // coalesced: s = lane
    }
    #pragma unroll
    for (int off = 32; off >= 1; off >>= 1) {
        lmin = fminf(lmin, __shfl_xor(lmin, off, 64));
        lmax = fmaxf(lmax, __shfl_xor(lmax, off, 64));
    }
    if ((t & 63) == 0) { rmin[t >> 6] = lmin; rmax[t >> 6] = lmax; }
    __syncthreads();
    if (t == 0) {
        minp[bid] = fminf(fminf(rmin[0], rmin[1]), fminf(rmin[2], rmin[3]));
        maxp[bid] = fmaxf(fmaxf(rmax[0], rmax[1]), fmaxf(rmax[2], rmax[3]));
    }
}

// ---------------- stage 3: finalize scalar constants ----------------
__global__ __launch_bounds__(256) void stage_consts(const float* __restrict__ stdsum,
                                                    const float* __restrict__ minp,
                                                    const float* __restrict__ maxp,
                                                    float* __restrict__ consts) {
    __shared__ float sh[256];
    const int t = threadIdx.x;
    sh[t] = (t < 32) ? stdsum[t] : 0.f;
    __syncthreads();
    for (int off = 128; off >= 1; off >>= 1) { if (t < off) sh[t] += sh[t + off]; __syncthreads(); }
    const float stdv = sh[0] * (1.0f / 1024.0f);
    __syncthreads();
    sh[t] = minp[t];
    __syncthreads();
    for (int off = 128; off >= 1; off >>= 1) { if (t < off) sh[t] = fminf(sh[t], sh[t + off]); __syncthreads(); }
    const float mn = sh[0];
    __syncthreads();
    sh[t] = maxp[t];
    __syncthreads();
    for (int off = 128; off >= 1; off >>= 1) { if (t < off) sh[t] = fmaxf(sh[t], sh[t + off]); __syncthreads(); }
    const float mx = sh[0];
    if (t == 0) {
        const float left  = mn / stdv;   // min/max commute with positive scale
        const float right = mx / stdv;
        // bw = 1.06 * 512^(-0.2) * mean(std(matrix/std)) ; the mean == 1 by construction
        const float bw = 1.06f * 0.28717458874925877f;
        const float delta = (right - left) * (1.0f / 512.0f);
        const float gstep = (right - left) * (1.0f / 511.0f);
        const float divisor = 2.5066282746310002f * bw;   // sqrt(2*pi)*bw
        const float inv2bw2 = 0.5f / (bw * bw);
        consts[0] = stdv;
        consts[1] = 1.0f / stdv;
        consts[2] = left;
        consts[3] = right;
        consts[4] = delta;
        consts[5] = delta * 0.5f / divisor;               // applied once at the end
        consts[6] = -(inv2bw2 * 1.4426950408889634f);     // exp(x) = exp2(x*log2 e)
        consts[7] = gstep;
    }
}

// ---------------- stage 4 (hot): KDE + pairwise L1 over grid ----------------
// One block per (l,f); thread g owns grid point g. Padded samples (proj==0 for
// s>=len) are skipped — mathematically identical to the reference's corr-term
// subtraction, and ~25% less work.
__global__ __launch_bounds__(512) void stage_kde(const float* __restrict__ PT,
                                                 const int* __restrict__ data_len,
                                                 const float* __restrict__ consts,
                                                 float* __restrict__ pair_out) {
    const int l = blockIdx.x >> 5;
    const int f = blockIdx.x & 31;
    const int g = threadIdx.x;
    __shared__ __align__(16) float xs[4][512];
    __shared__ float wred[8][8];
    const float invstd = consts[1];
    const float left   = consts[2];
    const float negc   = consts[6];
    const float gstep  = consts[7];
    #pragma unroll
    for (int e = 0; e < 4; ++e)
        xs[e][g] = PT[(size_t)(((e << 3) + l) * 32 + f) * 512 + g] * invstd;
    __syncthreads();
    const float p = fmaf((float)g, gstep, left);
    float red[4];
    #pragma unroll
    for (int e = 0; e < 4; ++e) {
        const int len = data_len[(e << 3) + l];       // uniform across block
        const float* __restrict__ x = xs[e];
        float a0 = 0.f, a1 = 0.f, a2 = 0.f, a3 = 0.f;
        int s = 0;
        for (; s + 4 <= len; s += 4) {
            float4 v = *reinterpret_cast<const float4*>(&x[s]);  // ds_read_b128 broadcast
            float d0 = v.x - p, d1 = v.y - p, d2 = v.z - p, d3 = v.w - p;
            a0 += fast_exp2(negc * d0 * d0);
            a1 += fast_exp2(negc * d1 * d1);
            a2 += fast_exp2(negc * d2 * d2);
            a3 += fast_exp2(negc * d3 * d3);
        }
        for (; s < len; ++s) {
            float d = x[s] - p;
            a0 += fast_exp2(negc * d * d);
        }
        red[e] = ((a0 + a1) + (a2 + a3)) / (float)len;
    }
    // pairs in test_idx order: (0,1),(0,2),(0,3),(1,2),(1,3),(2,3)
    float pr[6];
    pr[0] = fabsf(red[0] - red[1]);
    pr[1] = fabsf(red[0] - red[2]);
    pr[2] = fabsf(red[0] - red[3]);
    pr[3] = fabsf(red[1] - red[2]);
    pr[4] = fabsf(red[1] - red[3]);
    pr[5] = fabsf(red[2] - red[3]);
    #pragma unroll
    for (int pi = 0; pi < 6; ++pi) {
        float v = pr[pi];
        #pragma unroll
        for (int off = 32; off >= 1; off >>= 1) v += __shfl_xor(v, off, 64);
        if ((threadIdx.x & 63) == 0) wred[threadIdx.x >> 6][pi] = v;
    }
    __syncthreads();
    if (threadIdx.x < 6) {
        float s = 0.f;
        #pragma unroll
        for (int w = 0; w < 8; ++w) s += wred[w][threadIdx.x];
        pair_out[threadIdx.x * 256 + blockIdx.x] = s;   // [pair][l*32+f]
    }
}

// ---------------- stage 5: maxes, scaling, scalar outputs ----------------
__global__ __launch_bounds__(256) void stage_final(const float* __restrict__ pair_out,
                                                   const float* __restrict__ consts,
                                                   float* __restrict__ out) {
    const int t = threadIdx.x;              // (l,f) = (t>>5, t&31)
    const float scale = consts[5];
    float v[6];
    #pragma unroll
    for (int pi = 0; pi < 6; ++pi) v[pi] = pair_out[pi * 256 + t] * scale;
    float testv = v[0];
    #pragma unroll
    for (int pi = 1; pi < 6; ++pi) testv = fmaxf(testv, v[pi]);
    const float trainv = fmaxf(fmaxf(v[0], v[1]), v[3]);  // pairs (0,1),(0,2),(1,2)
    out[t] = trainv;        // train_results (L,F)
    out[256 + t] = testv;   // test_results  (L,F)
    __shared__ float str[256], ste[256];
    str[t] = trainv; ste[t] = testv;
    __syncthreads();
    if (t < 32) {           // max over l for fixed f
        float mt = str[t], me = ste[t];
        for (int lrow = 1; lrow < 8; ++lrow) {
            mt = fmaxf(mt, str[lrow * 32 + t]);
            me = fmaxf(me, ste[lrow * 32 + t]);
        }
        str[t] = mt; ste[t] = me;
    }
    __syncthreads();
    if (t == 0) {           // mean over f
        float smt = 0.f, sme = 0.f;
        for (int k = 0; k < 32; ++k) { smt += str[k]; sme += ste[k]; }
        out[512] = smt * (1.0f / 32.0f);   // train_dis
        out[513] = sme * (1.0f / 32.0f);   // test_dis
    }
}

extern "C" void kernel_launch(void* const* d_in, const int* in_sizes, int n_in,
                              void* d_out, int out_size, void* d_ws, size_t ws_size,
                              hipStream_t stream) {
    (void)in_sizes; (void)n_in; (void)out_size; (void)ws_size;
    const float* matrix = (const float*)d_in[0];
    const float* params = (const float*)d_in[1];
    const int*   dlen   = (const int*)d_in[2];
    float* out = (float*)d_out;
    float* ws  = (float*)d_ws;
    float* PT      = ws + PT_OFF;
    float* stdsum  = ws + STD_OFF;
    float* minp    = ws + MIN_OFF;
    float* maxp    = ws + MAX_OFF;
    float* consts  = ws + CONST_OFF;
    float* pairsum = ws + PAIR_OFF;

    hipLaunchKernelGGL(stage_std,    dim3(32),  dim3(256), 0, stream, matrix, stdsum);
    hipLaunchKernelGGL(stage_proj,   dim3(256), dim3(256), 0, stream, matrix, params, PT, minp, maxp);
    hipLaunchKernelGGL(stage_consts, dim3(1),   dim3(256), 0, stream, stdsum, minp, maxp, consts);
    hipLaunchKernelGGL(stage_kde,    dim3(256), dim3(512), 0, stream, PT, dlen, consts, pairsum);
    hipLaunchKernelGGL(stage_final,  dim3(1),   dim3(256), 0, stream, pairsum, consts, out);
}

// Round 2
// 102.217 us; speedup vs baseline: 1.2276x; 1.2276x over previous
//
#include <hip/hip_runtime.h>
#include <float.h>

// E=4, L=8, S=512, F=32, G=512 grid points.

#if __has_builtin(__builtin_amdgcn_exp2f)
__device__ __forceinline__ float fast_exp2(float x) { return __builtin_amdgcn_exp2f(x); }
#else
__device__ __forceinline__ float fast_exp2(float x) { return exp2f(x); }
#endif

// ---- workspace layout (float offsets) ----
#define PT_OFF    0        // proj^T [E][L][F][S] = 524288 floats (unscaled)
#define SX_OFF    524288   // per-block per-f sum(x)   [256][32]
#define SXX_OFF   532480   // per-block per-f sum(x^2) [256][32]
#define MIN_OFF   540672   // 256 per-block mins
#define MAX_OFF   540928   // 256 per-block maxs
#define CONST_OFF 541184   // 16 scalars
#define PAIR_OFF  541200   // 6*1024 pair partials
// total ~547K floats = 2.2 MB

// consts: [0]=std [1]=1/std [2]=left [3]=right [4]=delta [5]=scale [6]=negc [7]=gstep

// ---------- stage 1: proj (transposed) + per-f std partials + min/max ----------
__global__ __launch_bounds__(256) void stage_prep(const float* __restrict__ matrix,
                                                  const float* __restrict__ params,
                                                  float* __restrict__ PT,
                                                  float* __restrict__ sxg,
                                                  float* __restrict__ sxxg,
                                                  float* __restrict__ minp,
                                                  float* __restrict__ maxp) {
    __shared__ float M[64][33];    // +1 pad: proj pass reads column-wise
    __shared__ float Pm[32][32];
    __shared__ float sxr[8][32], sxxr[8][32];
    __shared__ float rmin[4], rmax[4];
    const int bid = blockIdx.x;        // (e*8+l)*8 + stile
    const int s0 = (bid & 7) << 6;
    const int el = bid >> 3;
    const int t = threadIdx.x;
    for (int k = t; k < 1024; k += 256) Pm[k >> 5][k & 31] = params[k];
    const float* mb = matrix + (size_t)(el * 512 + s0) * 32;
    for (int k = t; k < 2048; k += 256) M[k >> 5][k & 31] = mb[k];
    __syncthreads();
    // ---- std partials: thread (r=t>>5, f=t&31) sums 8 rows ----
    {
        const int f = t & 31, r = t >> 5;
        float sx = 0.f, sxx = 0.f;
        #pragma unroll
        for (int k = 0; k < 8; ++k) {
            float v = M[r * 8 + k][f];
            sx += v; sxx += v * v;
        }
        sxr[r][f] = sx; sxxr[r][f] = sxx;
    }
    // ---- proj: thread (s=t&63, g0=t>>6), 8 passes of 4 g ----
    const int s = t & 63;
    const int g0 = t >> 6;
    float lmin = FLT_MAX, lmax = -FLT_MAX;
    #pragma unroll
    for (int pass = 0; pass < 8; ++pass) {
        const int g = (pass << 2) + g0;
        float acc = 0.f;
        #pragma unroll
        for (int fp = 0; fp < 32; ++fp) acc += M[s][fp] * Pm[fp][g];
        lmin = fminf(lmin, acc);
        lmax = fmaxf(lmax, acc);
        PT[(size_t)(el * 32 + g) * 512 + s0 + s] = acc;
    }
    #pragma unroll
    for (int off = 32; off >= 1; off >>= 1) {
        lmin = fminf(lmin, __shfl_xor(lmin, off, 64));
        lmax = fmaxf(lmax, __shfl_xor(lmax, off, 64));
    }
    if ((t & 63) == 0) { rmin[t >> 6] = lmin; rmax[t >> 6] = lmax; }
    __syncthreads();
    if (t < 32) {
        float a = 0.f, b = 0.f;
        #pragma unroll
        for (int r = 0; r < 8; ++r) { a += sxr[r][t]; b += sxxr[r][t]; }
        sxg[bid * 32 + t] = a;
        sxxg[bid * 32 + t] = b;
    }
    if (t == 0) {
        minp[bid] = fminf(fminf(rmin[0], rmin[1]), fminf(rmin[2], rmin[3]));
        maxp[bid] = fmaxf(fmaxf(rmax[0], rmax[1]), fmaxf(rmax[2], rmax[3]));
    }
}

// ---------- stage 2: finalize scalar constants ----------
__global__ __launch_bounds__(512) void stage_consts(const float* __restrict__ sxg,
                                                    const float* __restrict__ sxxg,
                                                    const float* __restrict__ minp,
                                                    const float* __restrict__ maxp,
                                                    float* __restrict__ consts) {
    const int t = threadIdx.x;
    __shared__ float wsum[8], wmin[8], wmax[8];
    float stdloc = 0.f;
    #pragma unroll
    for (int tr = t; tr < 1024; tr += 512) {      // (e,l,f) triple
        const int el = tr >> 5, f = tr & 31;
        const int base = el * 256 + f;            // sxg[(el*8+tile)*32+f]
        float sx = 0.f, sxx = 0.f;
        #pragma unroll
        for (int tile = 0; tile < 8; ++tile) { sx += sxg[base + tile * 32]; sxx += sxxg[base + tile * 32]; }
        float mean = sx * (1.0f / 512.0f);
        float var = (sxx - sx * mean) * (1.0f / 511.0f);   // ddof=1
        stdloc += sqrtf(fmaxf(var, 0.f));
    }
    float mn = (t < 256) ? minp[t] : FLT_MAX;
    float mx = (t < 256) ? maxp[t] : -FLT_MAX;
    #pragma unroll
    for (int off = 32; off >= 1; off >>= 1) {
        stdloc += __shfl_xor(stdloc, off, 64);
        mn = fminf(mn, __shfl_xor(mn, off, 64));
        mx = fmaxf(mx, __shfl_xor(mx, off, 64));
    }
    if ((t & 63) == 0) { wsum[t >> 6] = stdloc; wmin[t >> 6] = mn; wmax[t >> 6] = mx; }
    __syncthreads();
    if (t == 0) {
        float s = 0.f, lo = FLT_MAX, hi = -FLT_MAX;
        #pragma unroll
        for (int w = 0; w < 8; ++w) { s += wsum[w]; lo = fminf(lo, wmin[w]); hi = fmaxf(hi, wmax[w]); }
        const float stdv = s * (1.0f / 1024.0f);
        const float left  = lo / stdv;
        const float right = hi / stdv;
        const float bw = 1.06f * 0.28717458874925877f;     // mean(std(m)) == 1 exactly
        const float delta = (right - left) * (1.0f / 512.0f);
        const float gstep = (right - left) * (1.0f / 511.0f);
        const float divisor = 2.5066282746310002f * bw;
        const float inv2bw2 = 0.5f / (bw * bw);
        consts[0] = stdv;
        consts[1] = 1.0f / stdv;
        consts[2] = left;
        consts[3] = right;
        consts[4] = delta;
        consts[5] = delta * 0.5f / divisor;
        consts[6] = -(inv2bw2 * 1.4426950408889634f);      // exp(x)=exp2(x*log2e)
        consts[7] = gstep;
    }
}

// ---------- stage 3 (hot): KDE + pairwise L1 ----------
// 1024 blocks = (l,f,chunk); 512 threads = (e = t>>7, gl = t&127).
// arg = negc*(x-p)^2 = y[s] + B*x[s] + C with y = negc*x^2 staged in LDS:
// per sample fma+add+exp2+acc (3 VALU + 1 trans) vs 4+1 for the d-form.
__global__ __launch_bounds__(512) void stage_kde(const float* __restrict__ PT,
                                                 const int* __restrict__ data_len,
                                                 const float* __restrict__ consts,
                                                 float* __restrict__ pair_out) {
    const int bid = blockIdx.x;
    const int lf = bid >> 2, chunk = bid & 3;
    const int l = lf >> 5, f = lf & 31;
    const int t = threadIdx.x;
    const int e = t >> 7, gl = t & 127;
    __shared__ __align__(16) float xs[4][512];
    __shared__ __align__(16) float ys[4][512];
    __shared__ float sred[4][128];
    __shared__ float wred2[6][2];
    const float invstd = consts[1];
    const float left   = consts[2];
    const float negc   = consts[6];
    const float gstep  = consts[7];
    #pragma unroll
    for (int e2 = 0; e2 < 4; ++e2) {
        float v = PT[((size_t)(((e2 << 3) + l) * 32 + f) << 9) + t] * invstd;
        xs[e2][t] = v;
        ys[e2][t] = negc * v * v;
    }
    __syncthreads();
    const int g = (chunk << 7) + gl;
    const float p = fmaf((float)g, gstep, left);
    const float B = -2.0f * negc * p;
    const float C = negc * p * p;
    const int len = data_len[(e << 3) + l];       // wave-uniform
    const float* __restrict__ x = xs[e];
    const float* __restrict__ y = ys[e];
    float a0 = 0.f, a1 = 0.f, a2 = 0.f, a3 = 0.f;
    int s = 0;
    for (; s + 8 <= len; s += 8) {
        float4 xv0 = *reinterpret_cast<const float4*>(&x[s]);
        float4 xv1 = *reinterpret_cast<const float4*>(&x[s + 4]);
        float4 yv0 = *reinterpret_cast<const float4*>(&y[s]);
        float4 yv1 = *reinterpret_cast<const float4*>(&y[s + 4]);
        a0 += fast_exp2(fmaf(B, xv0.x, yv0.x) + C);
        a1 += fast_exp2(fmaf(B, xv0.y, yv0.y) + C);
        a2 += fast_exp2(fmaf(B, xv0.z, yv0.z) + C);
        a3 += fast_exp2(fmaf(B, xv0.w, yv0.w) + C);
        a0 += fast_exp2(fmaf(B, xv1.x, yv1.x) + C);
        a1 += fast_exp2(fmaf(B, xv1.y, yv1.y) + C);
        a2 += fast_exp2(fmaf(B, xv1.z, yv1.z) + C);
        a3 += fast_exp2(fmaf(B, xv1.w, yv1.w) + C);
    }
    for (; s < len; ++s)
        a0 += fast_exp2(fmaf(B, x[s], y[s]) + C);
    sred[e][gl] = ((a0 + a1) + (a2 + a3)) / (float)len;
    __syncthreads();
    if (t < 128) {
        const float r0 = sred[0][t], r1 = sred[1][t], r2 = sred[2][t], r3 = sred[3][t];
        float pr[6];
        pr[0] = fabsf(r0 - r1);
        pr[1] = fabsf(r0 - r2);
        pr[2] = fabsf(r0 - r3);
        pr[3] = fabsf(r1 - r2);
        pr[4] = fabsf(r1 - r3);
        pr[5] = fabsf(r2 - r3);
        #pragma unroll
        for (int pi = 0; pi < 6; ++pi) {
            float v = pr[pi];
            #pragma unroll
            for (int off = 32; off >= 1; off >>= 1) v += __shfl_xor(v, off, 64);
            if ((t & 63) == 0) wred2[pi][t >> 6] = v;
        }
    }
    __syncthreads();
    if (t < 6) pair_out[t * 1024 + bid] = wred2[t][0] + wred2[t][1];
}

// ---------- stage 4: chunk-sum, maxes, scaling, scalar outputs ----------
__global__ __launch_bounds__(256) void stage_final(const float* __restrict__ pair_out,
                                                   const float* __restrict__ consts,
                                                   float* __restrict__ out) {
    const int t = threadIdx.x;              // lf: (l,f)=(t>>5, t&31)
    const float scale = consts[5];
    float v[6];
    #pragma unroll
    for (int pi = 0; pi < 6; ++pi) {
        float s = 0.f;
        #pragma unroll
        for (int c = 0; c < 4; ++c) s += pair_out[pi * 1024 + t * 4 + c];
        v[pi] = s * scale;
    }
    float testv = v[0];
    #pragma unroll
    for (int pi = 1; pi < 6; ++pi) testv = fmaxf(testv, v[pi]);
    const float trainv = fmaxf(fmaxf(v[0], v[1]), v[3]);  // pairs (0,1),(0,2),(1,2)
    out[t] = trainv;
    out[256 + t] = testv;
    __shared__ float str[256], ste[256];
    str[t] = trainv; ste[t] = testv;
    __syncthreads();
    if (t < 32) {
        float mt = str[t], me = ste[t];
        for (int lrow = 1; lrow < 8; ++lrow) {
            mt = fmaxf(mt, str[lrow * 32 + t]);
            me = fmaxf(me, ste[lrow * 32 + t]);
        }
        str[t] = mt; ste[t] = me;
    }
    __syncthreads();
    if (t == 0) {
        float smt = 0.f, sme = 0.f;
        for (int k = 0; k < 32; ++k) { smt += str[k]; sme += ste[k]; }
        out[512] = smt * (1.0f / 32.0f);
        out[513] = sme * (1.0f / 32.0f);
    }
}

extern "C" void kernel_launch(void* const* d_in, const int* in_sizes, int n_in,
                              void* d_out, int out_size, void* d_ws, size_t ws_size,
                              hipStream_t stream) {
    (void)in_sizes; (void)n_in; (void)out_size; (void)ws_size;
    const float* matrix = (const float*)d_in[0];
    const float* params = (const float*)d_in[1];
    const int*   dlen   = (const int*)d_in[2];
    float* out = (float*)d_out;
    float* ws  = (float*)d_ws;
    float* PT      = ws + PT_OFF;
    float* sxg     = ws + SX_OFF;
    float* sxxg    = ws + SXX_OFF;
    float* minp    = ws + MIN_OFF;
    float* maxp    = ws + MAX_OFF;
    float* consts  = ws + CONST_OFF;
    float* pairsum = ws + PAIR_OFF;

    hipLaunchKernelGGL(stage_prep,   dim3(256),  dim3(256), 0, stream,
                       matrix, params, PT, sxg, sxxg, minp, maxp);
    hipLaunchKernelGGL(stage_consts, dim3(1),    dim3(512), 0, stream,
                       sxg, sxxg, minp, maxp, consts);
    hipLaunchKernelGGL(stage_kde,    dim3(1024), dim3(512), 0, stream,
                       PT, dlen, consts, pairsum);
    hipLaunchKernelGGL(stage_final,  dim3(1),    dim3(256), 0, stream,
                       pairsum, consts, out);
}